// Round 1
// baseline (92.550 us; speedup 1.0000x reference)
//
#include <hip/hip_runtime.h>

// Problem constants (B, L, C, H, W) = (2, 48, 8, 48, 48)
constexpr int B = 2, L = 48, C = 8, H = 48, W = 48;
constexpr int HW = H * W;   // 2304

// ---------------------------------------------------------------------------
// Kernel 1: cumulative sum of flows along L.
// flows layout: (B, L, 2, H, W). One thread per (b, comp, pixel) = 9216 threads,
// sequential scan over L in the same order as jnp.cumsum (float32).
// ---------------------------------------------------------------------------
__global__ void cumsum_kernel(const float* __restrict__ flows, float* __restrict__ cum) {
    int tid = blockIdx.x * blockDim.x + threadIdx.x;
    if (tid >= B * 2 * HW) return;
    int pix  = tid % HW;
    int comp = (tid / HW) & 1;
    int b    = tid / (2 * HW);
    const float* src = flows + (size_t)b * L * 2 * HW + (size_t)comp * HW + pix;
    float*       dst = cum   + (size_t)b * L * 2 * HW + (size_t)comp * HW + pix;
    float acc = 0.0f;
#pragma unroll
    for (int l = 0; l < L; ++l) {
        acc += src[(size_t)l * 2 * HW];
        dst[(size_t)l * 2 * HW] = acc;
    }
}

// ---------------------------------------------------------------------------
// Kernel 2: transpose images (B,L,C,H,W) -> (B,L,H,W,C) so each bilinear tap
// reads 8 contiguous channels (two float4 loads).
// ---------------------------------------------------------------------------
__global__ void transpose_kernel(const float* __restrict__ images, float* __restrict__ imgT) {
    int tid = blockIdx.x * blockDim.x + threadIdx.x;
    if (tid >= B * L * HW) return;
    int pix = tid % HW;
    int bl  = tid / HW;
    const float* src = images + (size_t)bl * C * HW + pix;
    float4 v0, v1;
    v0.x = src[0 * HW]; v0.y = src[1 * HW]; v0.z = src[2 * HW]; v0.w = src[3 * HW];
    v1.x = src[4 * HW]; v1.y = src[5 * HW]; v1.z = src[6 * HW]; v1.w = src[7 * HW];
    float4* dst = reinterpret_cast<float4*>(imgT + ((size_t)bl * HW + pix) * C);
    dst[0] = v0;
    dst[1] = v1;
}

// ---------------------------------------------------------------------------
// Kernel 3: main warp+scan.
// One thread per (b, t, pixel). k-loop 0..t; coordinates computed once per k,
// shared across the 8 channels accumulated in registers.
// grid = (HW/256, L, B), with blockIdx.y mapped to t = L-1-y so the heaviest
// blocks (t = L-1) are dispatched first (load-balance the tail).
// TR = true : img is channel-last (B,L,H,W,C), float4 taps.
// TR = false: img is original (B,L,C,H,W), scalar taps (ws too small fallback).
// ---------------------------------------------------------------------------
template <bool TR>
__global__ void warp_scan_kernel(const float* __restrict__ cum,
                                 const float* __restrict__ img,
                                 float* __restrict__ out) {
    int pix = blockIdx.x * blockDim.x + threadIdx.x;
    if (pix >= HW) return;
    int t = L - 1 - blockIdx.y;
    int b = blockIdx.z;
    int w = pix % W;
    int h = pix / W;

    // base grid (+1 pre-added on x so we wrap (gx_raw + 1) mod 2 directly)
    float base_gx_p1 = (2 * w + 1) * (1.0f / W);          // in (0, 2)
    float base_gy    = (2 * h + 1) * (1.0f / H) - 1.0f;

    const float* cumb = cum + (size_t)b * L * 2 * HW + pix;
    float ctx = cumb[(size_t)(t * 2) * HW];
    float cty = cumb[(size_t)(t * 2 + 1) * HW];

    float acc[C];
#pragma unroll
    for (int c = 0; c < C; ++c) acc[c] = 0.0f;

    for (int k = 0; k <= t; ++k) {
        float relx = ctx - cumb[(size_t)(k * 2) * HW];
        float rely = cty - cumb[(size_t)(k * 2 + 1) * HW];

        // x wrap: m = remainder(base_gx + relx + 1, 2)  in [0, 2)
        // exact subtract/add ladder == fmod(v,2) + (+2 if negative), bit-identical
        // to jnp.remainder for |v| < 8.
        float v = base_gx_p1 + relx;
        v = (v >= 2.0f) ? v - 2.0f : v;
        v = (v >= 2.0f) ? v - 2.0f : v;
        v = (v >= 2.0f) ? v - 2.0f : v;
        v = (v <  0.0f) ? v + 2.0f : v;
        v = (v <  0.0f) ? v + 2.0f : v;
        v = (v <  0.0f) ? v + 2.0f : v;

        float ix = (v * (float)W - 1.0f) * 0.5f;                        // [-0.5, W-0.5]
        float gy = base_gy + rely;
        float iy = ((gy + 1.0f) * (float)H - 1.0f) * 0.5f;

        float x0f = floorf(ix), y0f = floorf(iy);
        float wx1 = ix - x0f,   wy1 = iy - y0f;
        float wx0 = 1.0f - wx1, wy0 = 1.0f - wy1;

        // tap validity on the UNCLAMPED floored coords (matches reference)
        float vx0 = (x0f >= 0.0f  && x0f <= (float)(W - 1)) ? 1.0f : 0.0f;
        float vx1 = (x0f >= -1.0f && x0f <= (float)(W - 2)) ? 1.0f : 0.0f;
        float vy0 = (y0f >= 0.0f  && y0f <= (float)(H - 1)) ? 1.0f : 0.0f;
        float vy1 = (y0f >= -1.0f && y0f <= (float)(H - 2)) ? 1.0f : 0.0f;

        int x0 = min(max((int)x0f, 0), W - 1);
        int x1 = min(max((int)x0f + 1, 0), W - 1);
        int y0 = min(max((int)y0f, 0), H - 1);
        int y1 = min(max((int)y0f + 1, 0), H - 1);

        float w00 = wx0 * wy0 * vx0 * vy0;
        float w10 = wx1 * wy0 * vx1 * vy0;
        float w01 = wx0 * wy1 * vx0 * vy1;
        float w11 = wx1 * wy1 * vx1 * vy1;

        if constexpr (TR) {
            const float* base = img + ((size_t)(b * L + k) * HW) * C;
            auto tap = [&](int y, int x, float wgt) {
                const float4* p = reinterpret_cast<const float4*>(base + (size_t)(y * W + x) * C);
                float4 q0 = p[0], q1 = p[1];
                acc[0] += wgt * q0.x; acc[1] += wgt * q0.y;
                acc[2] += wgt * q0.z; acc[3] += wgt * q0.w;
                acc[4] += wgt * q1.x; acc[5] += wgt * q1.y;
                acc[6] += wgt * q1.z; acc[7] += wgt * q1.w;
            };
            tap(y0, x0, w00);
            tap(y0, x1, w10);
            tap(y1, x0, w01);
            tap(y1, x1, w11);
        } else {
            const float* base = img + (size_t)(b * L + k) * C * HW;
            int o00 = y0 * W + x0, o10 = y0 * W + x1;
            int o01 = y1 * W + x0, o11 = y1 * W + x1;
#pragma unroll
            for (int c = 0; c < C; ++c) {
                const float* pc = base + (size_t)c * HW;
                acc[c] += w00 * pc[o00] + w10 * pc[o10] + w01 * pc[o01] + w11 * pc[o11];
            }
        }
    }

    float* o = out + (size_t)(b * L + t) * C * HW + pix;
#pragma unroll
    for (int c = 0; c < C; ++c) o[(size_t)c * HW] = acc[c];
}

// ---------------------------------------------------------------------------
extern "C" void kernel_launch(void* const* d_in, const int* in_sizes, int n_in,
                              void* d_out, int out_size, void* d_ws, size_t ws_size,
                              hipStream_t stream) {
    const float* flows  = (const float*)d_in[0];   // (B, L, 2, H, W) fp32
    const float* images = (const float*)d_in[1];   // (B, L, C, H, W) fp32
    float* out = (float*)d_out;                    // (B, L, C, H, W) fp32

    const size_t cum_elems  = (size_t)B * L * 2 * HW;   // 442,368 floats (1.77 MB)
    const size_t imgT_elems = (size_t)B * L * C * HW;   // 3,538,944 floats (14.2 MB)

    float* cum  = (float*)d_ws;
    float* imgT = cum + cum_elems;
    const bool use_tr = ws_size >= (cum_elems + imgT_elems) * sizeof(float);

    cumsum_kernel<<<(B * 2 * HW + 255) / 256, 256, 0, stream>>>(flows, cum);

    dim3 grid((HW + 255) / 256, L, B);
    if (use_tr) {
        transpose_kernel<<<(B * L * HW + 255) / 256, 256, 0, stream>>>(images, imgT);
        warp_scan_kernel<true><<<grid, 256, 0, stream>>>(cum, imgT, out);
    } else {
        warp_scan_kernel<false><<<grid, 256, 0, stream>>>(cum, images, out);
    }
}

// Round 2
// 91.876 us; speedup vs baseline: 1.0073x; 1.0073x over previous
//
#include <hip/hip_runtime.h>

// Problem constants (B, L, C, H, W) = (2, 48, 8, 48, 48)
constexpr int B = 2, L = 48, C = 8, H = 48, W = 48;
constexpr int HW = H * W;   // 2304

constexpr int PPB = 64;     // pixels per block
constexpr int SL  = 4;      // k-slices per block (threads = PPB*SL = 256)

// ---------------------------------------------------------------------------
// Kernel 1: cumulative sum of flows along L, written PACKED as float2:
// cum2 layout (B, L, HW, 2) so the main kernel's per-k coordinate load is one
// coalesced 8B load per lane. One thread per (b, comp, pixel); sequential fp32
// scan over L (same accumulation order as jnp.cumsum).
// ---------------------------------------------------------------------------
__global__ void cumsum_kernel(const float* __restrict__ flows, float* __restrict__ cum2) {
    int tid = blockIdx.x * blockDim.x + threadIdx.x;
    if (tid >= B * 2 * HW) return;
    int pix  = tid % HW;
    int comp = (tid / HW) & 1;
    int b    = tid / (2 * HW);
    const float* src = flows + (size_t)b * L * 2 * HW + (size_t)comp * HW + pix;
    float*       dst = cum2  + ((size_t)b * L * HW + pix) * 2 + comp;
    float acc = 0.0f;
#pragma unroll
    for (int l = 0; l < L; ++l) {
        acc += src[(size_t)l * 2 * HW];
        dst[(size_t)l * HW * 2] = acc;
    }
}

// ---------------------------------------------------------------------------
// Kernel 2: transpose images (B,L,C,H,W) -> (B,L,H,W,C) so each bilinear tap
// reads 8 contiguous channels (two float4 loads).
// ---------------------------------------------------------------------------
__global__ void transpose_kernel(const float* __restrict__ images, float* __restrict__ imgT) {
    int tid = blockIdx.x * blockDim.x + threadIdx.x;
    if (tid >= B * L * HW) return;
    int pix = tid % HW;
    int bl  = tid / HW;
    const float* src = images + (size_t)bl * C * HW + pix;
    float4 v0, v1;
    v0.x = src[0 * HW]; v0.y = src[1 * HW]; v0.z = src[2 * HW]; v0.w = src[3 * HW];
    v1.x = src[4 * HW]; v1.y = src[5 * HW]; v1.z = src[6 * HW]; v1.w = src[7 * HW];
    float4* dst = reinterpret_cast<float4*>(imgT + ((size_t)bl * HW + pix) * C);
    dst[0] = v0;
    dst[1] = v1;
}

// ---------------------------------------------------------------------------
// Kernel 3: main warp+scan, k-sliced for occupancy.
// Block = 256 threads = 64 pixels (lanes, coalesced) x 4 k-slices.
// Slice s handles k in {s, s+SL, s+2*SL, ...} <= t; 8-channel accumulator in
// registers; slices combined via an 8 KB LDS reduction; coalesced store.
// grid = (HW/PPB, L, B) = (36, 48, 2) = 3456 blocks; t = L-1-blockIdx.y so the
// heaviest blocks launch first.
// ---------------------------------------------------------------------------
__global__ void warp_scan_kernel(const float* __restrict__ cum2,
                                 const float* __restrict__ imgT,
                                 float* __restrict__ out) {
    const int p   = threadIdx.x & (PPB - 1);   // pixel within group (lane)
    const int s   = threadIdx.x >> 6;          // k-slice 0..SL-1
    const int pix = blockIdx.x * PPB + p;
    const int t   = L - 1 - blockIdx.y;
    const int b   = blockIdx.z;
    const int w   = pix % W;
    const int h   = pix / W;

    // base grid (+1 pre-added on x so we wrap (gx_raw + 1) mod 2 directly)
    const float base_gx_p1 = (2 * w + 1) * (1.0f / W);          // in (0, 2)
    const float base_gy    = (2 * h + 1) * (1.0f / H) - 1.0f;

    const float* cb = cum2 + ((size_t)b * L * HW + pix) * 2;    // + k*HW*2 per k
    const float2 ct = *reinterpret_cast<const float2*>(cb + (size_t)t * HW * 2);
    const float ctx = ct.x, cty = ct.y;

    float acc[C];
#pragma unroll
    for (int c = 0; c < C; ++c) acc[c] = 0.0f;

    for (int k = s; k <= t; k += SL) {
        const float2 ck = *reinterpret_cast<const float2*>(cb + (size_t)k * HW * 2);
        float relx = ctx - ck.x;
        float rely = cty - ck.y;

        // x wrap: remainder(base_gx + relx + 1, 2) in [0,2); exact ladder,
        // bit-identical to jnp.remainder for |v| < 8.
        float v = base_gx_p1 + relx;
        v = (v >= 2.0f) ? v - 2.0f : v;
        v = (v >= 2.0f) ? v - 2.0f : v;
        v = (v >= 2.0f) ? v - 2.0f : v;
        v = (v <  0.0f) ? v + 2.0f : v;
        v = (v <  0.0f) ? v + 2.0f : v;
        v = (v <  0.0f) ? v + 2.0f : v;

        float ix = (v * (float)W - 1.0f) * 0.5f;
        float gy = base_gy + rely;
        float iy = ((gy + 1.0f) * (float)H - 1.0f) * 0.5f;

        float x0f = floorf(ix), y0f = floorf(iy);
        float wx1 = ix - x0f,   wy1 = iy - y0f;
        float wx0 = 1.0f - wx1, wy0 = 1.0f - wy1;

        // tap validity on the UNCLAMPED floored coords (matches reference)
        float vx0 = (x0f >= 0.0f  && x0f <= (float)(W - 1)) ? 1.0f : 0.0f;
        float vx1 = (x0f >= -1.0f && x0f <= (float)(W - 2)) ? 1.0f : 0.0f;
        float vy0 = (y0f >= 0.0f  && y0f <= (float)(H - 1)) ? 1.0f : 0.0f;
        float vy1 = (y0f >= -1.0f && y0f <= (float)(H - 2)) ? 1.0f : 0.0f;

        int x0 = min(max((int)x0f, 0), W - 1);
        int x1 = min(max((int)x0f + 1, 0), W - 1);
        int y0 = min(max((int)y0f, 0), H - 1);
        int y1 = min(max((int)y0f + 1, 0), H - 1);

        float w00 = wx0 * wy0 * vx0 * vy0;
        float w10 = wx1 * wy0 * vx1 * vy0;
        float w01 = wx0 * wy1 * vx0 * vy1;
        float w11 = wx1 * wy1 * vx1 * vy1;

        const float* base = imgT + ((size_t)(b * L + k) * HW) * C;
        auto tap = [&](int y, int x, float wgt) {
            const float4* q = reinterpret_cast<const float4*>(base + (size_t)(y * W + x) * C);
            float4 q0 = q[0], q1 = q[1];
            acc[0] += wgt * q0.x; acc[1] += wgt * q0.y;
            acc[2] += wgt * q0.z; acc[3] += wgt * q0.w;
            acc[4] += wgt * q1.x; acc[5] += wgt * q1.y;
            acc[6] += wgt * q1.z; acc[7] += wgt * q1.w;
        };
        tap(y0, x0, w00);
        tap(y0, x1, w10);
        tap(y1, x0, w01);
        tap(y1, x1, w11);
    }

    // reduce across the SL slices via LDS: red[slice][ch][pix] (8 KB)
    __shared__ float red[SL][C][PPB];
#pragma unroll
    for (int c = 0; c < C; ++c) red[s][c][p] = acc[c];
    __syncthreads();

    // 256 threads -> 512 outputs: thread (s,p) handles channels s and s+SL
    float* ob = out + (size_t)(b * L + t) * C * HW + pix;
#pragma unroll
    for (int cc = s; cc < C; cc += SL) {
        float vsum = red[0][cc][p] + red[1][cc][p] + red[2][cc][p] + red[3][cc][p];
        ob[(size_t)cc * HW] = vsum;
    }
}

// ---------------------------------------------------------------------------
extern "C" void kernel_launch(void* const* d_in, const int* in_sizes, int n_in,
                              void* d_out, int out_size, void* d_ws, size_t ws_size,
                              hipStream_t stream) {
    const float* flows  = (const float*)d_in[0];   // (B, L, 2, H, W) fp32
    const float* images = (const float*)d_in[1];   // (B, L, C, H, W) fp32
    float* out = (float*)d_out;                    // (B, L, C, H, W) fp32

    const size_t cum_elems  = (size_t)B * L * 2 * HW;   // 442,368 floats (1.77 MB)

    float* cum2 = (float*)d_ws;
    float* imgT = cum2 + cum_elems;

    cumsum_kernel<<<(B * 2 * HW + 255) / 256, 256, 0, stream>>>(flows, cum2);
    transpose_kernel<<<(B * L * HW + 255) / 256, 256, 0, stream>>>(images, imgT);

    dim3 grid(HW / PPB, L, B);
    warp_scan_kernel<<<grid, 256, 0, stream>>>(cum2, imgT, out);
}

// Round 3
// 58.140 us; speedup vs baseline: 1.5918x; 1.5802x over previous
//
#include <hip/hip_runtime.h>
#include <hip/hip_fp16.h>

// Problem constants (B, L, C, H, W) = (2, 48, 8, 48, 48)
constexpr int B = 2, L = 48, C = 8, H = 48, W = 48;
constexpr int HW = H * W;   // 2304

constexpr int PPB = 64;     // pixels per block
constexpr int SL  = 4;      // k-slices per block (threads = PPB*SL = 256)

// ---------------------------------------------------------------------------
// Kernel 1: cumulative sum of flows along L, written PACKED as float2:
// cum2 layout (B, L, HW, 2) so the main kernel's per-k coordinate load is one
// coalesced 8B load per lane. fp32 scan, same accumulation order as jnp.cumsum.
// ---------------------------------------------------------------------------
__global__ void cumsum_kernel(const float* __restrict__ flows, float* __restrict__ cum2) {
    int tid = blockIdx.x * blockDim.x + threadIdx.x;
    if (tid >= B * 2 * HW) return;
    int pix  = tid % HW;
    int comp = (tid / HW) & 1;
    int b    = tid / (2 * HW);
    const float* src = flows + (size_t)b * L * 2 * HW + (size_t)comp * HW + pix;
    float*       dst = cum2  + ((size_t)b * L * HW + pix) * 2 + comp;
    float acc = 0.0f;
#pragma unroll
    for (int l = 0; l < L; ++l) {
        acc += src[(size_t)l * 2 * HW];
        dst[(size_t)l * HW * 2] = acc;
    }
}

// ---------------------------------------------------------------------------
// Kernel 2: convert images (B,L,C,H,W) fp32 -> (B,L,H,W,C) fp16 channel-last.
// One bilinear tap then reads all 8 channels with a single 16B load.
// ---------------------------------------------------------------------------
__global__ void convert_kernel(const float* __restrict__ images, __half* __restrict__ imgH) {
    int tid = blockIdx.x * blockDim.x + threadIdx.x;
    if (tid >= B * L * HW) return;
    int pix = tid % HW;
    int bl  = tid / HW;
    const float* src = images + (size_t)bl * C * HW + pix;
    __half h[C];
#pragma unroll
    for (int c = 0; c < C; ++c) h[c] = __float2half(src[(size_t)c * HW]);
    float4* dst = reinterpret_cast<float4*>(imgH + ((size_t)bl * HW + pix) * C);
    *dst = *reinterpret_cast<float4*>(h);
}

// ---------------------------------------------------------------------------
// Kernel 3: main warp+scan, k-sliced, fp16 channel-last taps.
// Block = 256 threads = 64 pixels (lanes, coalesced) x 4 k-slices.
// Slice s handles k in {s, s+SL, ...} <= t; 8 fp32 accumulators in registers;
// slices combined via an 8 KB LDS reduction; coalesced store.
// grid = (36, 48, 2); t = L-1-blockIdx.y (heaviest blocks first).
// ---------------------------------------------------------------------------
__global__ void warp_scan_kernel(const float* __restrict__ cum2,
                                 const __half* __restrict__ imgH,
                                 float* __restrict__ out) {
    const int p   = threadIdx.x & (PPB - 1);   // pixel within group (lane)
    const int s   = threadIdx.x >> 6;          // k-slice 0..SL-1
    const int pix = blockIdx.x * PPB + p;
    const int t   = L - 1 - blockIdx.y;
    const int b   = blockIdx.z;
    const int w   = pix % W;
    const int h   = pix / W;

    // base grid (+1 pre-added on x so we wrap (gx_raw + 1) mod 2 directly)
    const float base_gx_p1 = (2 * w + 1) * (1.0f / W);          // in (0, 2)
    const float base_gy    = (2 * h + 1) * (1.0f / H) - 1.0f;

    const float* cb = cum2 + ((size_t)b * L * HW + pix) * 2;    // + k*HW*2 per k
    const float2 ct = *reinterpret_cast<const float2*>(cb + (size_t)t * HW * 2);
    const float ctx = ct.x, cty = ct.y;

    float acc[C];
#pragma unroll
    for (int c = 0; c < C; ++c) acc[c] = 0.0f;

    for (int k = s; k <= t; k += SL) {
        const float2 ck = *reinterpret_cast<const float2*>(cb + (size_t)k * HW * 2);
        float relx = ctx - ck.x;
        float rely = cty - ck.y;

        // x wrap: remainder(base_gx + relx + 1, 2) in [0,2); exact ladder,
        // bit-identical to jnp.remainder for |v| < 8.
        float v = base_gx_p1 + relx;
        v = (v >= 2.0f) ? v - 2.0f : v;
        v = (v >= 2.0f) ? v - 2.0f : v;
        v = (v >= 2.0f) ? v - 2.0f : v;
        v = (v <  0.0f) ? v + 2.0f : v;
        v = (v <  0.0f) ? v + 2.0f : v;
        v = (v <  0.0f) ? v + 2.0f : v;

        float ix = (v * (float)W - 1.0f) * 0.5f;
        float gy = base_gy + rely;
        float iy = ((gy + 1.0f) * (float)H - 1.0f) * 0.5f;

        float x0f = floorf(ix), y0f = floorf(iy);
        float wx1 = ix - x0f,   wy1 = iy - y0f;
        float wx0 = 1.0f - wx1, wy0 = 1.0f - wy1;

        // tap validity on the UNCLAMPED floored coords (matches reference)
        float vx0 = (x0f >= 0.0f  && x0f <= (float)(W - 1)) ? 1.0f : 0.0f;
        float vx1 = (x0f >= -1.0f && x0f <= (float)(W - 2)) ? 1.0f : 0.0f;
        float vy0 = (y0f >= 0.0f  && y0f <= (float)(H - 1)) ? 1.0f : 0.0f;
        float vy1 = (y0f >= -1.0f && y0f <= (float)(H - 2)) ? 1.0f : 0.0f;

        int x0 = min(max((int)x0f, 0), W - 1);
        int x1 = min(max((int)x0f + 1, 0), W - 1);
        int y0 = min(max((int)y0f, 0), H - 1);
        int y1 = min(max((int)y0f + 1, 0), H - 1);

        float w00 = wx0 * wy0 * vx0 * vy0;
        float w10 = wx1 * wy0 * vx1 * vy0;
        float w01 = wx0 * wy1 * vx0 * vy1;
        float w11 = wx1 * wy1 * vx1 * vy1;

        const __half* base = imgH + ((size_t)(b * L + k) * HW) * C;
        auto tap = [&](int y, int x, float wgt) {
            float4 raw = *reinterpret_cast<const float4*>(base + (size_t)(y * W + x) * C);
            const __half2* hc = reinterpret_cast<const __half2*>(&raw);
#pragma unroll
            for (int c = 0; c < 4; ++c) {
                float2 f = __half22float2(hc[c]);
                acc[2 * c]     += wgt * f.x;
                acc[2 * c + 1] += wgt * f.y;
            }
        };
        tap(y0, x0, w00);
        tap(y0, x1, w10);
        tap(y1, x0, w01);
        tap(y1, x1, w11);
    }

    // reduce across the SL slices via LDS: red[slice][ch][pix] (8 KB)
    __shared__ float red[SL][C][PPB];
#pragma unroll
    for (int c = 0; c < C; ++c) red[s][c][p] = acc[c];
    __syncthreads();

    // 256 threads -> 512 outputs: thread (s,p) handles channels s and s+SL
    float* ob = out + (size_t)(b * L + t) * C * HW + pix;
#pragma unroll
    for (int cc = s; cc < C; cc += SL) {
        float vsum = red[0][cc][p] + red[1][cc][p] + red[2][cc][p] + red[3][cc][p];
        ob[(size_t)cc * HW] = vsum;
    }
}

// ---------------------------------------------------------------------------
extern "C" void kernel_launch(void* const* d_in, const int* in_sizes, int n_in,
                              void* d_out, int out_size, void* d_ws, size_t ws_size,
                              hipStream_t stream) {
    const float* flows  = (const float*)d_in[0];   // (B, L, 2, H, W) fp32
    const float* images = (const float*)d_in[1];   // (B, L, C, H, W) fp32
    float* out = (float*)d_out;                    // (B, L, C, H, W) fp32

    const size_t cum_elems = (size_t)B * L * 2 * HW;   // 442,368 floats (1.77 MB)

    float*  cum2 = (float*)d_ws;
    __half* imgH = (__half*)(cum2 + cum_elems);        // 7.08 MB fp16 channel-last

    cumsum_kernel<<<(B * 2 * HW + 255) / 256, 256, 0, stream>>>(flows, cum2);
    convert_kernel<<<(B * L * HW + 255) / 256, 256, 0, stream>>>(images, imgH);

    dim3 grid(HW / PPB, L, B);
    warp_scan_kernel<<<grid, 256, 0, stream>>>(cum2, imgH, out);
}